// Round 15
// baseline (77.629 us; speedup 1.0000x reference)
//
#include <hip/hip_runtime.h>
#include <math.h>

#define L 4096
#define C2 32
#define CTOT 64
#define BB 4
#define NG 4
#define NSAMP 2048
#define TPB 256
#define ROWSPB 64            // per block: 2 row-tiles (rt) x 2 sample-halves (sh)
#define WS_B 196608          // 64 tiles x 3072 B presplit B-data

typedef _Float16 half8 __attribute__((ext_vector_type(8)));
typedef float f32x16 __attribute__((ext_vector_type(16)));

__device__ __forceinline__ void split3(float x, _Float16& h, _Float16& m, _Float16& l) {
    h = (_Float16)x; float r1 = x - (float)h;
    m = (_Float16)r1; float r2 = r1 - (float)m;
    l = (_Float16)r2;
}

// ---- prep: presplit B samples only (8 blocks; A is computed in-main) ----
// B tile = n>>5 (3072 B): level*1024 + kh*512 + col*16; kh0 = s^2, kh1 = s.
__global__ __launch_bounds__(256) void presplit_kernel(
    const float* __restrict__ prior, char* __restrict__ ws)
{
    int n = blockIdx.x * 256 + threadIdx.x;
    const float4* p4 = (const float4*)prior;
    float4 u = p4[2 * n], v = p4[2 * n + 1];
    float s[8] = {u.x, u.y, u.z, u.w, v.x, v.y, v.z, v.w};
    half8 qh, qm, ql, vh, vm, vl;
    #pragma unroll
    for (int g = 0; g < 8; ++g) {
        _Float16 hh, mm, ll;
        split3(s[g] * s[g], hh, mm, ll);
        qh[g] = hh; qm[g] = mm; ql[g] = ll;
        split3(s[g], hh, mm, ll);
        vh[g] = hh; vm[g] = mm; vl[g] = ll;
    }
    char* tb = ws + (size_t)(n >> 5) * 3072 + (size_t)(n & 31) * 16;
    *(half8*)(tb + 0)    = qh;
    *(half8*)(tb + 512)  = vh;
    *(half8*)(tb + 1024) = qm;
    *(half8*)(tb + 1536) = vm;
    *(half8*)(tb + 2048) = ql;
    *(half8*)(tb + 2560) = vl;
}

__device__ __forceinline__ void argmax16(const f32x16& acc, int tt,
                                         float* best, int* bt) {
    #pragma unroll
    for (int j = 0; j < 16; ++j) {
        bool gt = acc[j] > best[j];
        best[j] = gt ? acc[j] : best[j];
        bt[j]   = gt ? tt : bt[j];
    }
}

// ---- main: R14 structure (2 rt x 2 sh waves, 1024 blocks, dual-acc deferred
// argmax) + 3-deep B prefetch (P,Q,R rotate, period-6) + in-main A (once per
// wave; prep-A kernel dropped). Numerics identical to R7..R14 (3-way f16
// split, 6 MFMA terms; absmax 0 every round).
// D: col=lane&31, row=(reg&3)+8*(reg>>2)+4*(lane>>5) (HW-validated).
__global__ __launch_bounds__(TPB) void gqreg_main(
    const float* __restrict__ z, const float* __restrict__ prior,
    float* __restrict__ out, const char* __restrict__ wsb, int bws)
{
    __shared__ float mbB[2][2][2][16];   // [rt][sh][kh][j]
    __shared__ int   mbI[2][2][2][16];

    const int tid = threadIdx.x;
    const int lane = tid & 63;
    const int w = tid >> 6;
    const int rt = w >> 1;
    const int sh = w & 1;
    const int col = lane & 31;
    const int kh = lane >> 5;
    const float4* p4 = (const float4*)prior;
    const int rowbase = blockIdx.x * ROWSPB + rt * 32;

    // ---- A fragments: computed in-kernel once per wave (z is L2-resident) ----
    half8 ah, am, al;
    {
        int r = rowbase + col;
        int b = r >> 14, pos = (r >> 2) & (L - 1), ns = r & 3;
        const float* zb = z + (size_t)b * CTOT * L + pos;
        #pragma unroll
        for (int g = 0; g < 8; ++g) {
            float mu = zb[(size_t)(g * NG + ns) * L];
            float lv = zb[(size_t)(C2 + g * NG + ns) * L];
            lv = fminf(fmaxf(lv, -30.f), 20.f);
            float iv = expf(-lv);
            float x = kh ? (mu * iv) : (0.5f - 0.5f * iv);
            _Float16 xh, xm, xl;
            split3(x, xh, xm, xl);
            ah[g] = xh; am[g] = xm; al[g] = xl;
        }
    }

    float best[16];
    int bt[16];
    #pragma unroll
    for (int j = 0; j < 16; ++j) { best[j] = -INFINITY; bt[j] = 0; }
    const f32x16 z16 = {};

#define CHAIN(dst, Bh_, Bm_, Bl_)                                              \
    do {                                                                       \
        __builtin_amdgcn_s_setprio(1);                                         \
        dst = __builtin_amdgcn_mfma_f32_32x32x16_f16(ah, Bh_, z16, 0, 0, 0);   \
        dst = __builtin_amdgcn_mfma_f32_32x32x16_f16(ah, Bm_, dst, 0, 0, 0);   \
        dst = __builtin_amdgcn_mfma_f32_32x32x16_f16(am, Bh_, dst, 0, 0, 0);   \
        dst = __builtin_amdgcn_mfma_f32_32x32x16_f16(am, Bm_, dst, 0, 0, 0);   \
        dst = __builtin_amdgcn_mfma_f32_32x32x16_f16(ah, Bl_, dst, 0, 0, 0);   \
        dst = __builtin_amdgcn_mfma_f32_32x32x16_f16(al, Bh_, dst, 0, 0, 0);   \
        __builtin_amdgcn_s_setprio(0);                                         \
    } while (0)

#define LOADB(Bh_, Bm_, Bl_, t_)                                               \
    do {                                                                       \
        const char* q_ = base + (size_t)(t_) * 3072;                           \
        Bh_ = *(const half8*)(q_ + 0);                                         \
        Bm_ = *(const half8*)(q_ + 1024);                                      \
        Bl_ = *(const half8*)(q_ + 2048);                                      \
    } while (0)

    if (bws) {
        const char* base = wsb + (size_t)(sh * 32) * 3072 + (size_t)(kh * 512 + col * 16);
        const int tbase = sh * 32;
        half8 Ph, Pm, Pl, Qh, Qm, Ql, Rh, Rm, Rl;
        f32x16 aA, aB;
        LOADB(Ph, Pm, Pl, 0);
        LOADB(Qh, Qm, Ql, 1);
        LOADB(Rh, Rm, Rl, 2);
        // 5 iterations x 6 tiles = tiles 0..29; buffers reload 3 tiles ahead.
        for (int i = 0; i < 5; ++i) {
            const int t0 = 6 * i;
            CHAIN(aA, Ph, Pm, Pl);  LOADB(Ph, Pm, Pl, t0 + 3);
            if (i > 0) argmax16(aB, tbase + t0 - 1, best, bt);
            CHAIN(aB, Qh, Qm, Ql);  LOADB(Qh, Qm, Ql, t0 + 4);
            argmax16(aA, tbase + t0, best, bt);
            CHAIN(aA, Rh, Rm, Rl);  LOADB(Rh, Rm, Rl, t0 + 5);
            argmax16(aB, tbase + t0 + 1, best, bt);
            CHAIN(aB, Ph, Pm, Pl);  LOADB(Ph, Pm, Pl, t0 + 6);
            argmax16(aA, tbase + t0 + 2, best, bt);
            CHAIN(aA, Qh, Qm, Ql);  LOADB(Qh, Qm, Ql, t0 + 7);
            argmax16(aB, tbase + t0 + 3, best, bt);
            CHAIN(aB, Rh, Rm, Rl);
            if (i < 4) LOADB(Rh, Rm, Rl, t0 + 8);
            argmax16(aA, tbase + t0 + 4, best, bt);
        }
        // epilogue: tiles 30 (in P), 31 (in Q); aB pending from tile 29.
        argmax16(aB, tbase + 29, best, bt);
        CHAIN(aA, Ph, Pm, Pl);
        CHAIN(aB, Qh, Qm, Ql);
        argmax16(aA, tbase + 30, best, bt);
        argmax16(aB, tbase + 31, best, bt);
    } else {
        // fallback: split B in-VALU per tile (no ws)
        #pragma unroll 2
        for (int t = 0; t < 32; ++t) {
            const int tt = sh * 32 + t;
            int n = tt * 32 + col;
            float4 u = p4[2 * n], v = p4[2 * n + 1];
            float sv[8] = {u.x, u.y, u.z, u.w, v.x, v.y, v.z, v.w};
            half8 Bh, Bm, Bl;
            #pragma unroll
            for (int g = 0; g < 8; ++g) {
                float x = kh ? sv[g] : sv[g] * sv[g];
                _Float16 hh, mm, ll;
                split3(x, hh, mm, ll);
                Bh[g] = hh; Bm[g] = mm; Bl[g] = ll;
            }
            f32x16 acc;
            CHAIN(acc, Bh, Bm, Bl);
            argmax16(acc, tt, best, bt);
        }
    }
#undef CHAIN
#undef LOADB

    // ---- recover n; cross-col reduce within kh half (tie -> lowest n) ----
    int bn[16];
    #pragma unroll
    for (int j = 0; j < 16; ++j) bn[j] = bt[j] * 32 + col;
    #pragma unroll
    for (int j = 0; j < 16; ++j) {
        #pragma unroll
        for (int m = 1; m < 32; m <<= 1) {
            float os = __shfl_xor(best[j], m, 64);
            int oi = __shfl_xor(bn[j], m, 64);
            if (os > best[j] || (os == best[j] && oi < bn[j])) {
                best[j] = os; bn[j] = oi;
            }
        }
    }

    // ---- post per-wave results (2 active lanes/wave -> no conflicts) ----
    if (col == 0) {
        #pragma unroll
        for (int j = 0; j < 16; ++j) {
            mbB[rt][sh][kh][j] = best[j];
            mbI[rt][sh][kh][j] = bn[j];
        }
    }
    __syncthreads();

    // ---- wave 0 merges sample-halves (sh0 n < sh1 n: strict > keeps lowest)
    //      and writes all 64 rows, one per lane ----
    if (w == 0) {
        int rt_o = lane >> 5;
        int rr = lane & 31;
        int kh_o = (rr >> 2) & 1;
        int j_o = (rr & 3) | ((rr >> 3) << 2);
        float b0 = mbB[rt_o][0][kh_o][j_o];
        int i0 = mbI[rt_o][0][kh_o][j_o];
        float b1 = mbB[rt_o][1][kh_o][j_o];
        int i1 = mbI[rt_o][1][kh_o][j_o];
        int n = (b1 > b0) ? i1 : i0;
        int r = blockIdx.x * ROWSPB + rt_o * 32 + rr;
        int b = r >> 14, pos = (r >> 2) & (L - 1), ns = r & 3;
        out[(size_t)BB * C2 * L + ((size_t)b * NG + ns) * L + pos] = (float)n;
        float4 uu = p4[2 * n], vv = p4[2 * n + 1];
        float sv[8] = {uu.x, uu.y, uu.z, uu.w, vv.x, vv.y, vv.z, vv.w};
        #pragma unroll
        for (int g = 0; g < 8; ++g) {
            out[((size_t)b * C2 + g * NG + ns) * L + pos] = sv[g];
        }
    }
}

extern "C" void kernel_launch(void* const* d_in, const int* in_sizes, int n_in,
                              void* d_out, int out_size, void* d_ws, size_t ws_size,
                              hipStream_t stream) {
    const float* z = (const float*)d_in[0];
    const float* prior = (const float*)d_in[1];
    float* out = (float*)d_out;
    char* ws = (char*)d_ws;
    int bws = (ws_size >= (size_t)WS_B) ? 1 : 0;

    if (bws) {
        hipLaunchKernelGGL(presplit_kernel, dim3(NSAMP / 256), dim3(256), 0, stream,
                           prior, ws);
    }
    hipLaunchKernelGGL(gqreg_main, dim3((BB * L * NG) / ROWSPB), dim3(TPB), 0, stream,
                       z, prior, out, (const char*)ws, bws);
}